// Round 1
// baseline (1163.353 us; speedup 1.0000x reference)
//
#include <hip/hip_runtime.h>
#include <math.h>

// loss = -(1/N) * sum_i log(predicts[i, labels[i]])
// predicts: [N, C] float32, labels: [N] int, out: scalar float32.
// Strategy: pure gather (64 MiB of cachelines) instead of full 1 GiB read.

#ifndef MCEL_C
#define MCEL_C 256
#endif

__global__ __launch_bounds__(256) void mcel_gather_kernel(
    const float* __restrict__ predicts,
    const int*   __restrict__ labels,
    float* __restrict__ out,
    int n, float inv_n_neg)
{
    int i = blockIdx.x * blockDim.x + threadIdx.x;

    float v = 0.0f;
    if (i < n) {
        int lbl = labels[i];                       // coalesced
        float p = predicts[(size_t)i * MCEL_C + lbl]; // scattered, 1 line/lane
        v = logf(p);
    }

    // wave64 butterfly/down reduction
    #pragma unroll
    for (int off = 32; off > 0; off >>= 1)
        v += __shfl_down(v, off, 64);

    __shared__ float smem[4];                      // 256 threads = 4 waves
    int lane = threadIdx.x & 63;
    int wid  = threadIdx.x >> 6;
    if (lane == 0) smem[wid] = v;
    __syncthreads();

    if (threadIdx.x == 0) {
        float s = smem[0] + smem[1] + smem[2] + smem[3];
        atomicAdd(out, s * inv_n_neg);             // device-scope by default
    }
}

extern "C" void kernel_launch(void* const* d_in, const int* in_sizes, int n_in,
                              void* d_out, int out_size, void* d_ws, size_t ws_size,
                              hipStream_t stream) {
    const float* predicts = (const float*)d_in[0];
    const int*   labels   = (const int*)d_in[1];
    float*       out      = (float*)d_out;

    const int n = in_sizes[1];                     // N = number of rows/labels

    // d_out is poisoned with 0xAA before every timed launch — zero it first.
    hipMemsetAsync(out, 0, sizeof(float), stream);

    const int block = 256;
    const int grid  = (n + block - 1) / block;
    mcel_gather_kernel<<<grid, block, 0, stream>>>(predicts, labels, out,
                                                   n, -1.0f / (float)n);
}